// Round 1
// baseline (129.328 us; speedup 1.0000x reference)
//
#include <hip/hip_runtime.h>
#include <math.h>

#define NBATCH 8
#define NP 512
#define NS 512
#define DD 512
#define INV64 0.015625f
#define NEGBIG -1000000000.0f

// workspace float offsets
#define WS_M      0           // 512*512
#define WS_T      262144      // 8*512*512
#define WS_WV     2359296     // 512  (Wo @ Wval)
#define WS_U      2359808     // 512  (Wv @ wv)
#define WS_WQBK   2360320     // 512  (Wq @ bk)
#define WS_WKBQ   2360832     // 512  (Wk @ bq)
#define WS_VV     2361344     // 8*512
#define WS_A      2365440     // 8*512  piece·Wqbk
#define WS_E      2369536     // 8*512  slot·Wkbq
#define WS_CP     2373632     // 8*512
#define WS_CS     2377728     // 8*512
#define WS_TV     2381824     // 8*512  per-row value contribution
#define WS_SC     2385920     // [0]=c0=bv·wv [1]=c1=bo·Wval+bval [2]=sbb=bq·bk

#define OUT_SCORES 0
#define OUT_VALUE  2097152
#define OUT_COMP   2097160

__device__ inline float wave_dot512(const float* __restrict__ x,
                                    const float* __restrict__ y, int lane) {
  float4 x0 = *(const float4*)&x[lane * 4];
  float4 x1 = *(const float4*)&x[256 + lane * 4];
  float4 y0 = *(const float4*)&y[lane * 4];
  float4 y1 = *(const float4*)&y[256 + lane * 4];
  float s = x0.x * y0.x + x0.y * y0.y + x0.z * y0.z + x0.w * y0.w +
            x1.x * y1.x + x1.y * y1.y + x1.z * y1.z + x1.w * y1.w;
#pragma unroll
  for (int o = 32; o; o >>= 1) s += __shfl_down(s, o);
  return s;  // valid on lane 0
}

// job0: wv[r] = Wo[r,:]·Wval ; job1: Wqbk[r] = Wq[r,:]·bk ; job2: Wkbq[r] = Wk[r,:]·bq
__global__ __launch_bounds__(256) void k_pre1(const float* __restrict__ Wo,
                                              const float* __restrict__ Wval,
                                              const float* __restrict__ Wq,
                                              const float* __restrict__ bk,
                                              const float* __restrict__ Wk,
                                              const float* __restrict__ bq,
                                              float* __restrict__ ws) {
  int wid = blockIdx.x * 4 + (threadIdx.x >> 6);
  int lane = threadIdx.x & 63;
  int job = wid >> 9, r = wid & 511;
  const float *x, *y;
  float* dst;
  if (job == 0)      { x = Wo + (size_t)r * DD; y = Wval; dst = ws + WS_WV + r; }
  else if (job == 1) { x = Wq + (size_t)r * DD; y = bk;   dst = ws + WS_WQBK + r; }
  else               { x = Wk + (size_t)r * DD; y = bq;   dst = ws + WS_WKBQ + r; }
  float s = wave_dot512(x, y, lane);
  if (lane == 0) *dst = s;
}

// u[r] = Wv[r,:]·wv ; scalars c0,c1,sbb
__global__ __launch_bounds__(256) void k_pre2(const float* __restrict__ Wv,
                                              const float* __restrict__ bv,
                                              const float* __restrict__ bo,
                                              const float* __restrict__ Wval,
                                              const float* __restrict__ bq,
                                              const float* __restrict__ bk,
                                              const float* __restrict__ bval,
                                              float* __restrict__ ws) {
  int wid = blockIdx.x * 4 + (threadIdx.x >> 6);
  if (wid >= 515) return;
  int lane = threadIdx.x & 63;
  const float* wv = ws + WS_WV;
  const float *x, *y;
  float* dst;
  float extra = 0.f;
  if (wid < 512)       { x = Wv + (size_t)wid * DD; y = wv;   dst = ws + WS_U + wid; }
  else if (wid == 512) { x = bv; y = wv;   dst = ws + WS_SC + 0; }
  else if (wid == 513) { x = bo; y = Wval; dst = ws + WS_SC + 1; extra = *bval; }
  else                 { x = bq; y = bk;   dst = ws + WS_SC + 2; }
  float s = wave_dot512(x, y, lane);
  if (lane == 0) *dst = s + extra;
}

// 5 families of 4096 row-dots against a fixed 512-vector
__global__ __launch_bounds__(256) void k_rowdots(const float* __restrict__ piece,
                                                 const float* __restrict__ slot,
                                                 const float* __restrict__ Wc,
                                                 float* __restrict__ ws) {
  int wid = blockIdx.x * 4 + (threadIdx.x >> 6);  // 0..20479
  int lane = threadIdx.x & 63;
  int job = wid >> 12, r = wid & 4095;
  const float *x, *y;
  float* dst;
  float extra = 0.f;
  switch (job) {
    case 0:  x = piece + (size_t)r * DD; y = ws + WS_WQBK; dst = ws + WS_A + r; break;
    case 1:  x = slot + (size_t)r * DD;  y = ws + WS_WKBQ; dst = ws + WS_E + r; break;
    case 2:  x = slot + (size_t)r * DD;  y = ws + WS_U;    dst = ws + WS_VV + r; extra = ws[WS_SC + 0]; break;
    case 3:  x = piece + (size_t)r * DD; y = Wc;           dst = ws + WS_CP + r; break;
    default: x = slot + (size_t)r * DD;  y = Wc + DD;      dst = ws + WS_CS + r; break;
  }
  float s = wave_dot512(x, y, lane);
  if (lane == 0) *dst = s + extra;
}

// C[M,N] = A[M,K] @ B[K,N]   (row-major), 64x64 tile, BK=16, 256 thr, 4x4/thread
__global__ __launch_bounds__(256) void k_gemm_nn(const float* __restrict__ A,
                                                 const float* __restrict__ Bm,
                                                 float* __restrict__ C,
                                                 int M, int N, int K) {
  __shared__ float As[16][68];
  __shared__ float Bs[16][68];
  const int tx = threadIdx.x & 15, ty = threadIdx.x >> 4;
  const int m0 = blockIdx.x * 64, n0 = blockIdx.y * 64;
  const int a_m = threadIdx.x >> 2;
  const int a_k = (threadIdx.x & 3) << 2;
  const int b_k = threadIdx.x >> 4;
  const int b_n = (threadIdx.x & 15) << 2;
  float acc[4][4] = {};
  for (int k0 = 0; k0 < K; k0 += 16) {
    float4 av = *(const float4*)&A[(size_t)(m0 + a_m) * K + k0 + a_k];
    float4 bv = *(const float4*)&Bm[(size_t)(k0 + b_k) * N + n0 + b_n];
    As[a_k + 0][a_m] = av.x;
    As[a_k + 1][a_m] = av.y;
    As[a_k + 2][a_m] = av.z;
    As[a_k + 3][a_m] = av.w;
    *(float4*)&Bs[b_k][b_n] = bv;
    __syncthreads();
#pragma unroll
    for (int k = 0; k < 16; ++k) {
      float4 a4 = *(const float4*)&As[k][ty << 2];
      float4 b4 = *(const float4*)&Bs[k][tx << 2];
      float ar[4] = {a4.x, a4.y, a4.z, a4.w};
      float br[4] = {b4.x, b4.y, b4.z, b4.w};
#pragma unroll
      for (int i = 0; i < 4; ++i)
#pragma unroll
        for (int j = 0; j < 4; ++j) acc[i][j] = fmaf(ar[i], br[j], acc[i][j]);
    }
    __syncthreads();
  }
#pragma unroll
  for (int i = 0; i < 4; ++i) {
    float4 o = make_float4(acc[i][0], acc[i][1], acc[i][2], acc[i][3]);
    *(float4*)&C[(size_t)(m0 + (ty << 2) + i) * N + n0 + (tx << 2)] = o;
  }
}

// C[M,N] = A[M,K] @ Bt[N,K]^T  (both row-major)
__global__ __launch_bounds__(256) void k_gemm_nt(const float* __restrict__ A,
                                                 const float* __restrict__ Bt,
                                                 float* __restrict__ C,
                                                 int M, int N, int K) {
  __shared__ float As[16][68];
  __shared__ float Bs[16][68];
  const int tx = threadIdx.x & 15, ty = threadIdx.x >> 4;
  const int m0 = blockIdx.x * 64, n0 = blockIdx.y * 64;
  const int a_m = threadIdx.x >> 2;
  const int a_k = (threadIdx.x & 3) << 2;
  float acc[4][4] = {};
  for (int k0 = 0; k0 < K; k0 += 16) {
    float4 av = *(const float4*)&A[(size_t)(m0 + a_m) * K + k0 + a_k];
    float4 bv = *(const float4*)&Bt[(size_t)(n0 + a_m) * K + k0 + a_k];
    As[a_k + 0][a_m] = av.x;
    As[a_k + 1][a_m] = av.y;
    As[a_k + 2][a_m] = av.z;
    As[a_k + 3][a_m] = av.w;
    Bs[a_k + 0][a_m] = bv.x;
    Bs[a_k + 1][a_m] = bv.y;
    Bs[a_k + 2][a_m] = bv.z;
    Bs[a_k + 3][a_m] = bv.w;
    __syncthreads();
#pragma unroll
    for (int k = 0; k < 16; ++k) {
      float4 a4 = *(const float4*)&As[k][ty << 2];
      float4 b4 = *(const float4*)&Bs[k][tx << 2];
      float ar[4] = {a4.x, a4.y, a4.z, a4.w};
      float br[4] = {b4.x, b4.y, b4.z, b4.w};
#pragma unroll
      for (int i = 0; i < 4; ++i)
#pragma unroll
        for (int j = 0; j < 4; ++j) acc[i][j] = fmaf(ar[i], br[j], acc[i][j]);
    }
    __syncthreads();
  }
#pragma unroll
  for (int i = 0; i < 4; ++i) {
    float4 o = make_float4(acc[i][0], acc[i][1], acc[i][2], acc[i][3]);
    *(float4*)&C[(size_t)(m0 + (ty << 2) + i) * N + n0 + (tx << 2)] = o;
  }
}

// scores[b,p,s] = (T[b,p]·slot[b,s] + a[b,p] + e[b,s] + sbb)/64 + bias, masked
__global__ __launch_bounds__(256) void k_scores(const float* __restrict__ Tm,
                                                const float* __restrict__ slot,
                                                const float* __restrict__ sbias,
                                                const int* __restrict__ mask,
                                                const float* __restrict__ ws,
                                                float* __restrict__ out) {
  __shared__ float As[16][68];
  __shared__ float Bs[16][68];
  const int b = blockIdx.z;
  const float* A = Tm + (size_t)b * NP * DD;
  const float* Bt = slot + (size_t)b * NS * DD;
  const int tx = threadIdx.x & 15, ty = threadIdx.x >> 4;
  const int m0 = blockIdx.x * 64, n0 = blockIdx.y * 64;
  const int a_m = threadIdx.x >> 2;
  const int a_k = (threadIdx.x & 3) << 2;
  float acc[4][4] = {};
  for (int k0 = 0; k0 < DD; k0 += 16) {
    float4 av = *(const float4*)&A[(size_t)(m0 + a_m) * DD + k0 + a_k];
    float4 bv = *(const float4*)&Bt[(size_t)(n0 + a_m) * DD + k0 + a_k];
    As[a_k + 0][a_m] = av.x;
    As[a_k + 1][a_m] = av.y;
    As[a_k + 2][a_m] = av.z;
    As[a_k + 3][a_m] = av.w;
    Bs[a_k + 0][a_m] = bv.x;
    Bs[a_k + 1][a_m] = bv.y;
    Bs[a_k + 2][a_m] = bv.z;
    Bs[a_k + 3][a_m] = bv.w;
    __syncthreads();
#pragma unroll
    for (int k = 0; k < 16; ++k) {
      float4 a4 = *(const float4*)&As[k][ty << 2];
      float4 b4 = *(const float4*)&Bs[k][tx << 2];
      float ar[4] = {a4.x, a4.y, a4.z, a4.w};
      float br[4] = {b4.x, b4.y, b4.z, b4.w};
#pragma unroll
      for (int i = 0; i < 4; ++i)
#pragma unroll
        for (int j = 0; j < 4; ++j) acc[i][j] = fmaf(ar[i], br[j], acc[i][j]);
    }
    __syncthreads();
  }
  const float sbb = ws[WS_SC + 2];
  const float* av_p = ws + WS_A + b * NP;
  const float* ev_p = ws + WS_E + b * NS;
#pragma unroll
  for (int i = 0; i < 4; ++i) {
    int p = m0 + (ty << 2) + i;
    int s = n0 + (tx << 2);
    size_t base = ((size_t)b * NP + p) * NS + s;
    float avv = av_p[p];
    float4 ev = *(const float4*)&ev_p[s];
    float4 bsv = *(const float4*)&sbias[base];
    int4 mk = *(const int4*)&mask[base];
    float4 o;
    o.x = (mk.x == 0) ? NEGBIG : fmaf(acc[i][0] + avv + ev.x + sbb, INV64, bsv.x);
    o.y = (mk.y == 0) ? NEGBIG : fmaf(acc[i][1] + avv + ev.y + sbb, INV64, bsv.y);
    o.z = (mk.z == 0) ? NEGBIG : fmaf(acc[i][2] + avv + ev.z + sbb, INV64, bsv.z);
    o.w = (mk.w == 0) ? NEGBIG : fmaf(acc[i][3] + avv + ev.w + sbb, INV64, bsv.w);
    *(float4*)&out[OUT_SCORES + base] = o;
  }
}

// per (b,p) row: t = (Σ exp(s-m)*vv) / (Σ exp(s-m)) / NP
__global__ __launch_bounds__(64) void k_smax(const float* __restrict__ scores,
                                             const float* __restrict__ vv,
                                             float* __restrict__ tv) {
  int row = blockIdx.x;  // b*512+p
  int b = row >> 9;
  int lane = threadIdx.x;
  const float* sr = scores + (size_t)row * NS;
  const float* vr = vv + b * NS;
  float4 s0 = *(const float4*)&sr[lane * 4];
  float4 s1 = *(const float4*)&sr[256 + lane * 4];
  float m = fmaxf(fmaxf(fmaxf(s0.x, s0.y), fmaxf(s0.z, s0.w)),
                  fmaxf(fmaxf(s1.x, s1.y), fmaxf(s1.z, s1.w)));
#pragma unroll
  for (int o = 32; o; o >>= 1) m = fmaxf(m, __shfl_xor(m, o));
  float4 v0 = *(const float4*)&vr[lane * 4];
  float4 v1 = *(const float4*)&vr[256 + lane * 4];
  float z = 0.f, w = 0.f, e;
  e = expf(s0.x - m); z += e; w += e * v0.x;
  e = expf(s0.y - m); z += e; w += e * v0.y;
  e = expf(s0.z - m); z += e; w += e * v0.z;
  e = expf(s0.w - m); z += e; w += e * v0.w;
  e = expf(s1.x - m); z += e; w += e * v1.x;
  e = expf(s1.y - m); z += e; w += e * v1.y;
  e = expf(s1.z - m); z += e; w += e * v1.z;
  e = expf(s1.w - m); z += e; w += e * v1.w;
#pragma unroll
  for (int o = 32; o; o >>= 1) {
    z += __shfl_xor(z, o);
    w += __shfl_xor(w, o);
  }
  if (lane == 0) tv[row] = (w / z) * (1.0f / NP);
}

__global__ __launch_bounds__(512) void k_value(const float* __restrict__ ws,
                                               float* __restrict__ out) {
  int b = threadIdx.x >> 6, lane = threadIdx.x & 63;
  const float* tv = ws + WS_TV + b * NP;
  float s = 0.f;
#pragma unroll
  for (int k = 0; k < 8; ++k) s += tv[k * 64 + lane];
#pragma unroll
  for (int o = 32; o; o >>= 1) s += __shfl_down(s, o);
  if (lane == 0) out[OUT_VALUE + b] = s + ws[WS_SC + 1];
}

__global__ __launch_bounds__(256) void k_compat(const float* __restrict__ ws,
                                                const float* __restrict__ bc,
                                                float* __restrict__ out) {
  int idx = blockIdx.x * 256 + threadIdx.x;
  int lin = idx << 2;
  int s = lin & (NS - 1);
  int p = (lin >> 9) & (NP - 1);
  int b = lin >> 18;
  float cp = ws[WS_CP + b * NP + p];
  float4 cs = *(const float4*)&ws[WS_CS + b * NS + s];
  float bcv = *bc;
  float4 o = make_float4(cp + cs.x + bcv, cp + cs.y + bcv, cp + cs.z + bcv,
                         cp + cs.w + bcv);
  *(float4*)&out[OUT_COMP + lin] = o;
}

extern "C" void kernel_launch(void* const* d_in, const int* in_sizes, int n_in,
                              void* d_out, int out_size, void* d_ws,
                              size_t ws_size, hipStream_t stream) {
  const float* piece = (const float*)d_in[0];
  const float* slot = (const float*)d_in[1];
  const int* mask = (const int*)d_in[2];
  const float* sbias = (const float*)d_in[3];
  const float* Wq = (const float*)d_in[4];
  const float* bq = (const float*)d_in[5];
  const float* Wk = (const float*)d_in[6];
  const float* bk = (const float*)d_in[7];
  const float* Wv = (const float*)d_in[8];
  const float* bv = (const float*)d_in[9];
  const float* Wo = (const float*)d_in[10];
  const float* bo = (const float*)d_in[11];
  const float* Wc = (const float*)d_in[12];
  const float* bc = (const float*)d_in[13];
  const float* Wval = (const float*)d_in[14];
  const float* bval = (const float*)d_in[15];
  float* out = (float*)d_out;
  float* ws = (float*)d_ws;

  hipLaunchKernelGGL(k_pre1, dim3(384), dim3(256), 0, stream, Wo, Wval, Wq, bk, Wk, bq, ws);
  hipLaunchKernelGGL(k_pre2, dim3(129), dim3(256), 0, stream, Wv, bv, bo, Wval, bq, bk, bval, ws);
  hipLaunchKernelGGL(k_gemm_nt, dim3(8, 8), dim3(256), 0, stream, Wq, Wk, ws + WS_M, 512, 512, 512);
  hipLaunchKernelGGL(k_gemm_nn, dim3(64, 8), dim3(256), 0, stream, piece, ws + WS_M, ws + WS_T, 4096, 512, 512);
  hipLaunchKernelGGL(k_rowdots, dim3(5120), dim3(256), 0, stream, piece, slot, Wc, ws);
  hipLaunchKernelGGL(k_scores, dim3(8, 8, 8), dim3(256), 0, stream, ws + WS_T, slot, sbias, mask, ws, out);
  hipLaunchKernelGGL(k_smax, dim3(4096), dim3(64), 0, stream, out, ws + WS_VV, ws + WS_TV);
  hipLaunchKernelGGL(k_value, dim3(1), dim3(512), 0, stream, ws, out);
  hipLaunchKernelGGL(k_compat, dim3(2048), dim3(256), 0, stream, ws, bc, out);
}

// Round 2
// 65.775 us; speedup vs baseline: 1.9662x; 1.9662x over previous
//
#include <hip/hip_runtime.h>
#include <math.h>

#define NP 512
#define NS 512
#define DD 512
#define INV64 0.015625f
#define NEGBIG -1000000000.0f

// ws float-slot offsets
#define WS_SLOTBF 0         // 8*512*512 bf16 -> 1048576 float slots
#define WS_WQBF   1048576   // 512*512 bf16 -> 131072 slots
#define WS_WKBF   1179648
#define WS_MTBF   1310720
#define WS_WV     1441792   // 512
#define WS_U      1442304   // 512
#define WS_WQBK   1442816   // 512
#define WS_WKBQ   1443328   // 512
#define WS_VV     1443840   // 4096
#define WS_A      1447936   // 4096
#define WS_E      1452032   // 4096
#define WS_CP     1456128   // 4096
#define WS_CS     1460224   // 4096
#define WS_TV     1464320   // 4096
#define WS_SC     1468416   // [0]=bv.wv [1]=bo.Wval+bval [2]=bq.bk

#define OUT_SCORES 0
#define OUT_VALUE  2097152
#define OUT_COMP   2097160

typedef short bf16x8 __attribute__((ext_vector_type(8)));
typedef float f32x4 __attribute__((ext_vector_type(4)));

__device__ __forceinline__ short f2bf(float f) {
  unsigned u = __builtin_bit_cast(unsigned, f);
  u += 0x7fffu + ((u >> 16) & 1u);
  return (short)(u >> 16);
}

__device__ __forceinline__ void async_copy16(const void* g, void* l) {
  __builtin_amdgcn_global_load_lds(
      (const __attribute__((address_space(1))) unsigned int*)g,
      (__attribute__((address_space(3))) unsigned int*)l, 16, 0, 0);
}

__device__ __forceinline__ float dot8(float4 a0, float4 a1, float4 b0, float4 b1) {
  return a0.x * b0.x + a0.y * b0.y + a0.z * b0.z + a0.w * b0.w +
         a1.x * b1.x + a1.y * b1.y + a1.z * b1.z + a1.w * b1.w;
}

__device__ __forceinline__ float wave_red(float s) {
#pragma unroll
  for (int o = 32; o; o >>= 1) s += __shfl_xor(s, o);
  return s;
}

__device__ inline float wave_dot512(const float* __restrict__ x,
                                    const float* __restrict__ y, int lane) {
  float4 x0 = *(const float4*)&x[lane * 8];
  float4 x1 = *(const float4*)&x[lane * 8 + 4];
  float4 y0 = *(const float4*)&y[lane * 8];
  float4 y1 = *(const float4*)&y[lane * 8 + 4];
  return wave_red(dot8(x0, x1, y0, y1));
}

// Wq, Wk -> bf16
__global__ __launch_bounds__(256) void k_cvtw(const float* __restrict__ Wq,
                                              const float* __restrict__ Wk,
                                              short* __restrict__ wqb,
                                              short* __restrict__ wkb) {
  int t = blockIdx.x * 256 + threadIdx.x;  // 0..65535
  const float* src;
  short* dst;
  int off;
  if (t < 32768) { src = Wq; dst = wqb; off = t * 8; }
  else           { src = Wk; dst = wkb; off = (t - 32768) * 8; }
  float4 v0 = *(const float4*)&src[off];
  float4 v1 = *(const float4*)&src[off + 4];
  bf16x8 o;
  o[0] = f2bf(v0.x); o[1] = f2bf(v0.y); o[2] = f2bf(v0.z); o[3] = f2bf(v0.w);
  o[4] = f2bf(v1.x); o[5] = f2bf(v1.y); o[6] = f2bf(v1.z); o[7] = f2bf(v1.w);
  *(bf16x8*)&dst[off] = o;
}

// job0: wv[r]=Wo[r,:]·Wval ; job1: Wqbk[r]=Wq[r,:]·bk ; job2: Wkbq[r]=Wk[r,:]·bq
__global__ __launch_bounds__(256) void k_pre1(const float* __restrict__ Wo,
                                              const float* __restrict__ Wval,
                                              const float* __restrict__ Wq,
                                              const float* __restrict__ bk,
                                              const float* __restrict__ Wk,
                                              const float* __restrict__ bq,
                                              float* __restrict__ ws) {
  int wid = blockIdx.x * 4 + (threadIdx.x >> 6);
  int lane = threadIdx.x & 63;
  int job = wid >> 9, r = wid & 511;
  const float *x, *y;
  float* dst;
  if (job == 0)      { x = Wo + (size_t)r * DD; y = Wval; dst = ws + WS_WV + r; }
  else if (job == 1) { x = Wq + (size_t)r * DD; y = bk;   dst = ws + WS_WQBK + r; }
  else               { x = Wk + (size_t)r * DD; y = bq;   dst = ws + WS_WKBQ + r; }
  float s = wave_dot512(x, y, lane);
  if (lane == 0) *dst = s;
}

// u[r] = Wv[r,:]·wv ; scalars
__global__ __launch_bounds__(256) void k_pre2(const float* __restrict__ Wv,
                                              const float* __restrict__ bv,
                                              const float* __restrict__ bo,
                                              const float* __restrict__ Wval,
                                              const float* __restrict__ bq,
                                              const float* __restrict__ bk,
                                              const float* __restrict__ bval,
                                              float* __restrict__ ws) {
  int wid = blockIdx.x * 4 + (threadIdx.x >> 6);
  if (wid >= 515) return;
  int lane = threadIdx.x & 63;
  const float* wv = ws + WS_WV;
  const float *x, *y;
  float* dst;
  float extra = 0.f;
  if (wid < 512)       { x = Wv + (size_t)wid * DD; y = wv;   dst = ws + WS_U + wid; }
  else if (wid == 512) { x = bv; y = wv;   dst = ws + WS_SC + 0; }
  else if (wid == 513) { x = bo; y = Wval; dst = ws + WS_SC + 1; extra = *bval; }
  else                 { x = bq; y = bk;   dst = ws + WS_SC + 2; }
  float s = wave_dot512(x, y, lane);
  if (lane == 0) *dst = s + extra;
}

// piece: bf16 convert + a = piece·Wqbk + cp = piece·Wc[:512]
__global__ __launch_bounds__(256) void k_prep_piece(const float* __restrict__ piece,
                                                    const float* __restrict__ Wc,
                                                    float* __restrict__ ws,
                                                    short* __restrict__ pbf) {
  int wid = blockIdx.x * 4 + (threadIdx.x >> 6);  // 0..4095
  int lane = threadIdx.x & 63;
  const float* row = piece + (size_t)wid * DD;
  float4 x0 = *(const float4*)&row[lane * 8];
  float4 x1 = *(const float4*)&row[lane * 8 + 4];
  bf16x8 o;
  o[0] = f2bf(x0.x); o[1] = f2bf(x0.y); o[2] = f2bf(x0.z); o[3] = f2bf(x0.w);
  o[4] = f2bf(x1.x); o[5] = f2bf(x1.y); o[6] = f2bf(x1.z); o[7] = f2bf(x1.w);
  *(bf16x8*)&pbf[(size_t)wid * DD + lane * 8] = o;
  const float* y = ws + WS_WQBK;
  float4 y0 = *(const float4*)&y[lane * 8];
  float4 y1 = *(const float4*)&y[lane * 8 + 4];
  float4 c0 = *(const float4*)&Wc[lane * 8];
  float4 c1 = *(const float4*)&Wc[lane * 8 + 4];
  float da = wave_red(dot8(x0, x1, y0, y1));
  float dc = wave_red(dot8(x0, x1, c0, c1));
  if (lane == 0) { ws[WS_A + wid] = da; ws[WS_CP + wid] = dc; }
}

// slot: bf16 convert + e = slot·Wkbq + vv = slot·u + c0 + cs = slot·Wc[512:]
__global__ __launch_bounds__(256) void k_prep_slot(const float* __restrict__ slot,
                                                   const float* __restrict__ Wc,
                                                   float* __restrict__ ws,
                                                   short* __restrict__ sbf) {
  int wid = blockIdx.x * 4 + (threadIdx.x >> 6);  // 0..4095
  int lane = threadIdx.x & 63;
  const float* row = slot + (size_t)wid * DD;
  float4 x0 = *(const float4*)&row[lane * 8];
  float4 x1 = *(const float4*)&row[lane * 8 + 4];
  bf16x8 o;
  o[0] = f2bf(x0.x); o[1] = f2bf(x0.y); o[2] = f2bf(x0.z); o[3] = f2bf(x0.w);
  o[4] = f2bf(x1.x); o[5] = f2bf(x1.y); o[6] = f2bf(x1.z); o[7] = f2bf(x1.w);
  *(bf16x8*)&sbf[(size_t)wid * DD + lane * 8] = o;
  const float* y = ws + WS_WKBQ;
  float4 y0 = *(const float4*)&y[lane * 8];
  float4 y1 = *(const float4*)&y[lane * 8 + 4];
  const float* u = ws + WS_U;
  float4 u0 = *(const float4*)&u[lane * 8];
  float4 u1 = *(const float4*)&u[lane * 8 + 4];
  const float* c = Wc + DD;
  float4 c0 = *(const float4*)&c[lane * 8];
  float4 c1 = *(const float4*)&c[lane * 8 + 4];
  float de = wave_red(dot8(x0, x1, y0, y1));
  float dv = wave_red(dot8(x0, x1, u0, u1));
  float dc = wave_red(dot8(x0, x1, c0, c1));
  if (lane == 0) {
    ws[WS_E + wid] = de;
    ws[WS_VV + wid] = dv + ws[WS_SC + 0];
    ws[WS_CS + wid] = dc;
  }
}

// stage NG granules (16B each) of a [rows][K] bf16 tile into LDS with XOR swizzle
template <int NG>
__device__ __forceinline__ void stage_tile(const short* __restrict__ G, int ldk,
                                           short* lds, int r0, int k0, int wave,
                                           int lane) {
#pragma unroll
  for (int h = 0; h < NG / 256; ++h) {
    int s = h * 256 + wave * 64 + lane;
    int row = s >> 2;
    int g = (s & 3) ^ ((row >> 1) & 3);
    async_copy16(G + (size_t)(r0 + row) * ldk + k0 + g * 8,
                 lds + (size_t)(h * 256 + wave * 64) * 8);
  }
}

// C = A[M,K] · B[N,K]^T, bf16 MFMA, tile 128x64, BK=32, 4 waves, double-buffered.
// MODE 0: store bf16 C (ldc = N). MODE 1: fused scores epilogue, batched on z.
template <int MODE>
__global__ __launch_bounds__(256) void k_mfma_nt(
    const short* __restrict__ A, const short* __restrict__ B, int K, int N,
    short* __restrict__ Cb, const float* __restrict__ ws,
    const float* __restrict__ sbias, const int* __restrict__ maskp,
    float* __restrict__ out) {
  __shared__ short As[2][128 * 32];
  __shared__ short Bs[2][64 * 32];
  const int wave = threadIdx.x >> 6, lane = threadIdx.x & 63;
  const int wr = wave >> 1, wc = wave & 1;
  const int li = lane & 15, g = lane >> 4;
  const int m0 = blockIdx.x * 128, n0 = blockIdx.y * 64;
  const int b = (MODE == 1) ? blockIdx.z : 0;
  const short* Ab = A + (size_t)b * 512 * K;
  const short* Bb = B + (size_t)b * 512 * K;

  f32x4 acc[4][2] = {};

  stage_tile<512>(Ab, K, &As[0][0], m0, 0, wave, lane);
  stage_tile<256>(Bb, K, &Bs[0][0], n0, 0, wave, lane);
  __syncthreads();
  int buf = 0;
  for (int k0 = 0; k0 < K; k0 += 32) {
    if (k0 + 32 < K) {
      stage_tile<512>(Ab, K, &As[buf ^ 1][0], m0, k0 + 32, wave, lane);
      stage_tile<256>(Bb, K, &Bs[buf ^ 1][0], n0, k0 + 32, wave, lane);
    }
    bf16x8 af[4], bfr[2];
#pragma unroll
    for (int am = 0; am < 4; ++am) {
      int row = wr * 64 + am * 16 + li;
      int gp = g ^ ((row >> 1) & 3);
      af[am] = *(const bf16x8*)&As[buf][row * 32 + gp * 8];
    }
#pragma unroll
    for (int bn = 0; bn < 2; ++bn) {
      int row = wc * 32 + bn * 16 + li;
      int gp = g ^ ((row >> 1) & 3);
      bfr[bn] = *(const bf16x8*)&Bs[buf][row * 32 + gp * 8];
    }
#pragma unroll
    for (int am = 0; am < 4; ++am)
#pragma unroll
      for (int bn = 0; bn < 2; ++bn)
        acc[am][bn] = __builtin_amdgcn_mfma_f32_16x16x32_bf16(
            af[am], bfr[bn], acc[am][bn], 0, 0, 0);
    __syncthreads();
    buf ^= 1;
  }

  if (MODE == 0) {
#pragma unroll
    for (int am = 0; am < 4; ++am)
#pragma unroll
      for (int i = 0; i < 4; ++i) {
        int grow = m0 + wr * 64 + am * 16 + g * 4 + i;
#pragma unroll
        for (int bn = 0; bn < 2; ++bn) {
          int gcol = n0 + wc * 32 + bn * 16 + li;
          Cb[(size_t)grow * N + gcol] = f2bf(acc[am][bn][i]);
        }
      }
  } else {
    const float sbb = ws[WS_SC + 2];
#pragma unroll
    for (int am = 0; am < 4; ++am)
#pragma unroll
      for (int i = 0; i < 4; ++i) {
        int p = m0 + wr * 64 + am * 16 + g * 4 + i;
        float av = ws[WS_A + b * NP + p] + sbb;
#pragma unroll
        for (int bn = 0; bn < 2; ++bn) {
          int s = n0 + wc * 32 + bn * 16 + li;
          size_t idx = ((size_t)b * NP + p) * NS + s;
          float ev = ws[WS_E + b * NS + s];
          float sc = fmaf(acc[am][bn][i] + av + ev, INV64, sbias[idx]);
          out[OUT_SCORES + idx] = (maskp[idx] == 0) ? NEGBIG : sc;
        }
      }
  }
}

// per (b,p) row: tv = (Σ exp(s-m)*vv) / (Σ exp(s-m)) / NP
__global__ __launch_bounds__(64) void k_smax(const float* __restrict__ scores,
                                             const float* __restrict__ vv,
                                             float* __restrict__ tv) {
  int row = blockIdx.x;  // b*512+p
  int bb = row >> 9;
  int lane = threadIdx.x;
  const float* sr = scores + (size_t)row * NS;
  const float* vr = vv + bb * NS;
  float4 s0 = *(const float4*)&sr[lane * 4];
  float4 s1 = *(const float4*)&sr[256 + lane * 4];
  float m = fmaxf(fmaxf(fmaxf(s0.x, s0.y), fmaxf(s0.z, s0.w)),
                  fmaxf(fmaxf(s1.x, s1.y), fmaxf(s1.z, s1.w)));
#pragma unroll
  for (int o = 32; o; o >>= 1) m = fmaxf(m, __shfl_xor(m, o));
  float4 v0 = *(const float4*)&vr[lane * 4];
  float4 v1 = *(const float4*)&vr[256 + lane * 4];
  float z = 0.f, w = 0.f, e;
  e = expf(s0.x - m); z += e; w += e * v0.x;
  e = expf(s0.y - m); z += e; w += e * v0.y;
  e = expf(s0.z - m); z += e; w += e * v0.z;
  e = expf(s0.w - m); z += e; w += e * v0.w;
  e = expf(s1.x - m); z += e; w += e * v1.x;
  e = expf(s1.y - m); z += e; w += e * v1.y;
  e = expf(s1.z - m); z += e; w += e * v1.z;
  e = expf(s1.w - m); z += e; w += e * v1.w;
#pragma unroll
  for (int o = 32; o; o >>= 1) {
    z += __shfl_xor(z, o);
    w += __shfl_xor(w, o);
  }
  if (lane == 0) tv[row] = (w / z) * (1.0f / NP);
}

__global__ __launch_bounds__(512) void k_value(const float* __restrict__ ws,
                                               float* __restrict__ out) {
  int bb = threadIdx.x >> 6, lane = threadIdx.x & 63;
  const float* tv = ws + WS_TV + bb * NP;
  float s = 0.f;
#pragma unroll
  for (int k = 0; k < 8; ++k) s += tv[k * 64 + lane];
#pragma unroll
  for (int o = 32; o; o >>= 1) s += __shfl_down(s, o);
  if (lane == 0) out[OUT_VALUE + bb] = s + ws[WS_SC + 1];
}

__global__ __launch_bounds__(256) void k_compat(const float* __restrict__ ws,
                                                const float* __restrict__ bc,
                                                float* __restrict__ out) {
  int idx = blockIdx.x * 256 + threadIdx.x;
  int lin = idx << 2;
  int s = lin & (NS - 1);
  int p = (lin >> 9) & (NP - 1);
  int bb = lin >> 18;
  float cp = ws[WS_CP + bb * NP + p];
  float4 cs = *(const float4*)&ws[WS_CS + bb * NS + s];
  float bcv = *bc;
  float4 o = make_float4(cp + cs.x + bcv, cp + cs.y + bcv, cp + cs.z + bcv,
                         cp + cs.w + bcv);
  *(float4*)&out[OUT_COMP + lin] = o;
}

extern "C" void kernel_launch(void* const* d_in, const int* in_sizes, int n_in,
                              void* d_out, int out_size, void* d_ws,
                              size_t ws_size, hipStream_t stream) {
  const float* piece = (const float*)d_in[0];
  const float* slot = (const float*)d_in[1];
  const int* mask = (const int*)d_in[2];
  const float* sbias = (const float*)d_in[3];
  const float* Wq = (const float*)d_in[4];
  const float* bq = (const float*)d_in[5];
  const float* Wk = (const float*)d_in[6];
  const float* bk = (const float*)d_in[7];
  const float* Wv = (const float*)d_in[8];
  const float* bv = (const float*)d_in[9];
  const float* Wo = (const float*)d_in[10];
  const float* bo = (const float*)d_in[11];
  const float* Wc = (const float*)d_in[12];
  const float* bc = (const float*)d_in[13];
  const float* Wval = (const float*)d_in[14];
  const float* bval = (const float*)d_in[15];
  float* out = (float*)d_out;
  float* ws = (float*)d_ws;

  short* pbf = (short*)out;                  // piece bf16 (scores region, consumed before overwrite)
  short* tbf = (short*)(out + OUT_COMP);     // T bf16 (comp region, consumed before overwrite)
  short* sbf = (short*)(ws + WS_SLOTBF);
  short* wqb = (short*)(ws + WS_WQBF);
  short* wkb = (short*)(ws + WS_WKBF);
  short* mtb = (short*)(ws + WS_MTBF);

  hipLaunchKernelGGL(k_cvtw, dim3(256), dim3(256), 0, stream, Wq, Wk, wqb, wkb);
  hipLaunchKernelGGL(k_pre1, dim3(384), dim3(256), 0, stream, Wo, Wval, Wq, bk, Wk, bq, ws);
  hipLaunchKernelGGL(k_pre2, dim3(129), dim3(256), 0, stream, Wv, bv, bo, Wval, bq, bk, bval, ws);
  hipLaunchKernelGGL(k_prep_piece, dim3(1024), dim3(256), 0, stream, piece, Wc, ws, pbf);
  hipLaunchKernelGGL(k_prep_slot, dim3(1024), dim3(256), 0, stream, slot, Wc, ws, sbf);
  // MT[j,k] = sum_d Wk[j,d] Wq[k,d]  (= M^T, M = Wq Wk^T)
  hipLaunchKernelGGL((k_mfma_nt<0>), dim3(4, 8), dim3(256), 0, stream,
                     wkb, wqb, 512, 512, mtb, (const float*)nullptr,
                     (const float*)nullptr, (const int*)nullptr, (float*)nullptr);
  // T = piece_bf · MT^T  (M rows = 4096)
  hipLaunchKernelGGL((k_mfma_nt<0>), dim3(32, 8), dim3(256), 0, stream,
                     pbf, mtb, 512, 512, tbf, (const float*)nullptr,
                     (const float*)nullptr, (const int*)nullptr, (float*)nullptr);
  // scores = T_bf · slot_bf^T  + epilogue
  hipLaunchKernelGGL((k_mfma_nt<1>), dim3(4, 8, 8), dim3(256), 0, stream,
                     tbf, sbf, 512, 512, (short*)nullptr, ws, sbias, mask, out);
  hipLaunchKernelGGL(k_smax, dim3(4096), dim3(64), 0, stream, out, ws + WS_VV, ws + WS_TV);
  hipLaunchKernelGGL(k_value, dim3(1), dim3(512), 0, stream, ws, out);
  hipLaunchKernelGGL(k_compat, dim3(2048), dim3(256), 0, stream, ws, bc, out);
}

// Round 3
// 54.099 us; speedup vs baseline: 2.3906x; 1.2158x over previous
//
#include <hip/hip_runtime.h>
#include <math.h>

#define NP 512
#define NS 512
#define DD 512
#define INV64 0.015625f
#define NEGBIG -1000000000.0f
#define LOG2E 1.4426950408889634f

// ws float-slot offsets
#define WS_SLOTBF 0         // 8*512*512 bf16 -> 1048576 float slots
#define WS_WQBF   1048576   // 512*512 bf16
#define WS_WKBF   1179648
#define WS_MTBF   1310720
#define WS_WV     1441792   // 512
#define WS_U      1442304   // 512
#define WS_WQBK   1442816   // 512
#define WS_WKBQ   1443328   // 512
#define WS_VV     1443840   // 4096
#define WS_A      1447936   // 4096
#define WS_E      1452032   // 4096
#define WS_CP     1456128   // 4096
#define WS_CS     1460224   // 4096
#define WS_TV     1464320   // 4096
#define WS_SC     1468416   // [0]=bv.wv [1]=bo.Wval+bval [2]=bq.bk

#define OUT_SCORES 0
#define OUT_VALUE  2097152
#define OUT_COMP   2097160

typedef short bf16x8 __attribute__((ext_vector_type(8)));
typedef float f32x4 __attribute__((ext_vector_type(4)));

__device__ __forceinline__ short f2bf(float f) {
  unsigned u = __builtin_bit_cast(unsigned, f);
  u += 0x7fffu + ((u >> 16) & 1u);
  return (short)(u >> 16);
}

__device__ __forceinline__ void async_copy16(const void* g, void* l) {
  __builtin_amdgcn_global_load_lds(
      (const __attribute__((address_space(1))) unsigned int*)g,
      (__attribute__((address_space(3))) unsigned int*)l, 16, 0, 0);
}

__device__ __forceinline__ float dot8(float4 a0, float4 a1, float4 b0, float4 b1) {
  return a0.x * b0.x + a0.y * b0.y + a0.z * b0.z + a0.w * b0.w +
         a1.x * b1.x + a1.y * b1.y + a1.z * b1.z + a1.w * b1.w;
}

__device__ __forceinline__ float wave_red(float s) {
#pragma unroll
  for (int o = 32; o; o >>= 1) s += __shfl_xor(s, o);
  return s;
}

__device__ inline float wave_dot512(const float* __restrict__ x,
                                    const float* __restrict__ y, int lane) {
  float4 x0 = *(const float4*)&x[lane * 8];
  float4 x1 = *(const float4*)&x[lane * 8 + 4];
  float4 y0 = *(const float4*)&y[lane * 8];
  float4 y1 = *(const float4*)&y[lane * 8 + 4];
  return wave_red(dot8(x0, x1, y0, y1));
}

// ---------------- kA: pre1 row-dots + Wq/Wk -> bf16 convert ----------------
__global__ __launch_bounds__(256) void kA(
    const float* __restrict__ Wo, const float* __restrict__ Wval,
    const float* __restrict__ Wq, const float* __restrict__ bk,
    const float* __restrict__ Wk, const float* __restrict__ bq,
    const float* __restrict__ bo, const float* __restrict__ bval,
    float* __restrict__ ws, short* __restrict__ wqb, short* __restrict__ wkb) {
  int blk = blockIdx.x;
  if (blk < 385) {
    int wid = blk * 4 + (threadIdx.x >> 6);
    int lane = threadIdx.x & 63;
    if (wid >= 1538) return;
    const float *x, *y;
    float* dst;
    float extra = 0.f;
    int r = wid & 511;
    if (wid < 512)       { x = Wo + (size_t)r * DD; y = Wval; dst = ws + WS_WV + r; }
    else if (wid < 1024) { x = Wq + (size_t)r * DD; y = bk;   dst = ws + WS_WQBK + r; }
    else if (wid < 1536) { x = Wk + (size_t)r * DD; y = bq;   dst = ws + WS_WKBQ + r; }
    else if (wid == 1536){ x = bo; y = Wval; dst = ws + WS_SC + 1; extra = *bval; }
    else                 { x = bq; y = bk;   dst = ws + WS_SC + 2; }
    float s = wave_dot512(x, y, lane);
    if (lane == 0) *dst = s + extra;
  } else {
    int t = (blk - 385) * 256 + threadIdx.x;  // 0..65535
    const float* src;
    short* dst;
    int off;
    if (t < 32768) { src = Wq; dst = wqb; off = t * 8; }
    else           { src = Wk; dst = wkb; off = (t - 32768) * 8; }
    float4 v0 = *(const float4*)&src[off];
    float4 v1 = *(const float4*)&src[off + 4];
    bf16x8 o;
    o[0] = f2bf(v0.x); o[1] = f2bf(v0.y); o[2] = f2bf(v0.z); o[3] = f2bf(v0.w);
    o[4] = f2bf(v1.x); o[5] = f2bf(v1.y); o[6] = f2bf(v1.z); o[7] = f2bf(v1.w);
    *(bf16x8*)&dst[off] = o;
  }
}

// stage NG granules (16B) of a [rows][512] bf16 tile into LDS, XOR-swizzled (4-wave)
template <int NG>
__device__ __forceinline__ void stage_tile4(const short* __restrict__ G,
                                            short* lds, int r0, int k0, int wave,
                                            int lane) {
#pragma unroll
  for (int h = 0; h < NG / 256; ++h) {
    int s = h * 256 + wave * 64 + lane;
    int row = s >> 2;
    int g = (s & 3) ^ ((row >> 1) & 3);
    async_copy16(G + (size_t)(r0 + row) * DD + k0 + g * 8,
                 lds + (size_t)(h * 256 + wave * 64) * 8);
  }
}

// ---------------- kB: u = Wv.wv, c0, and MT = Wk_bf . Wq_bf^T (4-wave MFMA) ---
__global__ __launch_bounds__(256) void kB(
    const float* __restrict__ Wv, const float* __restrict__ bv,
    const short* __restrict__ wkb, const short* __restrict__ wqb,
    float* __restrict__ ws, short* __restrict__ mtb) {
  __shared__ short As[2][128 * 32];
  __shared__ short Bs[2][64 * 32];
  if (blockIdx.x < 129) {
    int wid = blockIdx.x * 4 + (threadIdx.x >> 6);
    if (wid >= 513) return;
    int lane = threadIdx.x & 63;
    const float* wv = ws + WS_WV;
    const float *x, *y;
    float* dst;
    if (wid < 512) { x = Wv + (size_t)wid * DD; y = wv; dst = ws + WS_U + wid; }
    else           { x = bv; y = wv; dst = ws + WS_SC + 0; }
    float s = wave_dot512(x, y, lane);
    if (lane == 0) *dst = s;
    return;
  }
  int gb = blockIdx.x - 129;  // 0..31
  const int m0 = (gb & 3) * 128, n0 = (gb >> 2) * 64;
  const int wave = threadIdx.x >> 6, lane = threadIdx.x & 63;
  const int wr = wave >> 1, wc = wave & 1;
  const int li = lane & 15, g = lane >> 4;
  f32x4 acc[4][2] = {};
  stage_tile4<512>(wkb, &As[0][0], m0, 0, wave, lane);
  stage_tile4<256>(wqb, &Bs[0][0], n0, 0, wave, lane);
  __syncthreads();
  int buf = 0;
  for (int k0 = 0; k0 < DD; k0 += 32) {
    if (k0 + 32 < DD) {
      stage_tile4<512>(wkb, &As[buf ^ 1][0], m0, k0 + 32, wave, lane);
      stage_tile4<256>(wqb, &Bs[buf ^ 1][0], n0, k0 + 32, wave, lane);
    }
    bf16x8 af[4], bfr[2];
#pragma unroll
    for (int am = 0; am < 4; ++am) {
      int row = wr * 64 + am * 16 + li;
      int gp = g ^ ((row >> 1) & 3);
      af[am] = *(const bf16x8*)&As[buf][row * 32 + gp * 8];
    }
#pragma unroll
    for (int bn = 0; bn < 2; ++bn) {
      int row = wc * 32 + bn * 16 + li;
      int gp = g ^ ((row >> 1) & 3);
      bfr[bn] = *(const bf16x8*)&Bs[buf][row * 32 + gp * 8];
    }
#pragma unroll
    for (int am = 0; am < 4; ++am)
#pragma unroll
      for (int bn = 0; bn < 2; ++bn)
        acc[am][bn] = __builtin_amdgcn_mfma_f32_16x16x32_bf16(
            af[am], bfr[bn], acc[am][bn], 0, 0, 0);
    __syncthreads();
    buf ^= 1;
  }
#pragma unroll
  for (int am = 0; am < 4; ++am)
#pragma unroll
    for (int i = 0; i < 4; ++i) {
      int grow = m0 + wr * 64 + am * 16 + g * 4 + i;
#pragma unroll
      for (int bn = 0; bn < 2; ++bn) {
        int gcol = n0 + wc * 32 + bn * 16 + li;
        mtb[(size_t)grow * DD + gcol] = f2bf(acc[am][bn][i]);
      }
    }
}

// ---------------- kC: piece/slot prep (bf16 cvt + fused row-dots) ------------
__global__ __launch_bounds__(256) void kC(
    const float* __restrict__ piece, const float* __restrict__ slot,
    const float* __restrict__ Wc, float* __restrict__ ws,
    short* __restrict__ pbf, short* __restrict__ sbf) {
  int lane = threadIdx.x & 63;
  if (blockIdx.x < 1024) {
    int wid = blockIdx.x * 4 + (threadIdx.x >> 6);  // 0..4095
    const float* row = piece + (size_t)wid * DD;
    float4 x0 = *(const float4*)&row[lane * 8];
    float4 x1 = *(const float4*)&row[lane * 8 + 4];
    bf16x8 o;
    o[0] = f2bf(x0.x); o[1] = f2bf(x0.y); o[2] = f2bf(x0.z); o[3] = f2bf(x0.w);
    o[4] = f2bf(x1.x); o[5] = f2bf(x1.y); o[6] = f2bf(x1.z); o[7] = f2bf(x1.w);
    *(bf16x8*)&pbf[(size_t)wid * DD + lane * 8] = o;
    const float* y = ws + WS_WQBK;
    float4 y0 = *(const float4*)&y[lane * 8];
    float4 y1 = *(const float4*)&y[lane * 8 + 4];
    float4 c0 = *(const float4*)&Wc[lane * 8];
    float4 c1 = *(const float4*)&Wc[lane * 8 + 4];
    float da = wave_red(dot8(x0, x1, y0, y1));
    float dc = wave_red(dot8(x0, x1, c0, c1));
    if (lane == 0) { ws[WS_A + wid] = da; ws[WS_CP + wid] = dc; }
  } else {
    int wid = (blockIdx.x - 1024) * 4 + (threadIdx.x >> 6);  // 0..4095
    const float* row = slot + (size_t)wid * DD;
    float4 x0 = *(const float4*)&row[lane * 8];
    float4 x1 = *(const float4*)&row[lane * 8 + 4];
    bf16x8 o;
    o[0] = f2bf(x0.x); o[1] = f2bf(x0.y); o[2] = f2bf(x0.z); o[3] = f2bf(x0.w);
    o[4] = f2bf(x1.x); o[5] = f2bf(x1.y); o[6] = f2bf(x1.z); o[7] = f2bf(x1.w);
    *(bf16x8*)&sbf[(size_t)wid * DD + lane * 8] = o;
    const float* y = ws + WS_WKBQ;
    float4 y0 = *(const float4*)&y[lane * 8];
    float4 y1 = *(const float4*)&y[lane * 8 + 4];
    const float* u = ws + WS_U;
    float4 u0 = *(const float4*)&u[lane * 8];
    float4 u1 = *(const float4*)&u[lane * 8 + 4];
    const float* c = Wc + DD;
    float4 c0 = *(const float4*)&c[lane * 8];
    float4 c1 = *(const float4*)&c[lane * 8 + 4];
    float de = wave_red(dot8(x0, x1, y0, y1));
    float dv = wave_red(dot8(x0, x1, u0, u1));
    float dc = wave_red(dot8(x0, x1, c0, c1));
    if (lane == 0) {
      ws[WS_E + wid] = de;
      ws[WS_VV + wid] = dv + ws[WS_SC + 0];
      ws[WS_CS + wid] = dc;
    }
  }
}

// ---------- 8-wave GEMM: C = A[M,512] . B[N,512]^T, tile 128x64, BK=32 -------
// MODE 0: store bf16 C. MODE 1: fused scores epilogue, batched on z.
template <int MODE>
__global__ __launch_bounds__(512) void k_gemm8(
    const short* __restrict__ A, const short* __restrict__ B,
    short* __restrict__ Cb, const float* __restrict__ ws,
    const float* __restrict__ sbias, const int* __restrict__ maskp,
    float* __restrict__ out) {
  __shared__ short As[2][128 * 32];
  __shared__ short Bs[2][64 * 32];
  const int wave = threadIdx.x >> 6, lane = threadIdx.x & 63;
  const int wr = wave >> 1, wc = wave & 1;
  const int li = lane & 15, g = lane >> 4;
  const int m0 = blockIdx.x * 128, n0 = blockIdx.y * 64;
  const int b = (MODE == 1) ? blockIdx.z : 0;
  const short* Ab = A + (size_t)b * NP * DD;
  const short* Bb = B + (size_t)b * NS * DD;
  f32x4 acc[2][2] = {};

  auto stage = [&](int bufi, int k0) {
    int s = wave * 64 + lane;
    int row = s >> 2;
    int gg = (s & 3) ^ ((row >> 1) & 3);
    async_copy16(Ab + (size_t)(m0 + row) * DD + k0 + gg * 8,
                 &As[bufi][(wave * 64) * 8]);
    if (wave < 4) {
      async_copy16(Bb + (size_t)(n0 + row) * DD + k0 + gg * 8,
                   &Bs[bufi][(wave * 64) * 8]);
    }
  };

  stage(0, 0);
  __syncthreads();
  int buf = 0;
  for (int k0 = 0; k0 < DD; k0 += 32) {
    if (k0 + 32 < DD) stage(buf ^ 1, k0 + 32);
    bf16x8 af[2], bfv[2];
#pragma unroll
    for (int am = 0; am < 2; ++am) {
      int row = wr * 32 + am * 16 + li;
      int gp = g ^ ((row >> 1) & 3);
      af[am] = *(const bf16x8*)&As[buf][row * 32 + gp * 8];
    }
#pragma unroll
    for (int bn = 0; bn < 2; ++bn) {
      int row = wc * 32 + bn * 16 + li;
      int gp = g ^ ((row >> 1) & 3);
      bfv[bn] = *(const bf16x8*)&Bs[buf][row * 32 + gp * 8];
    }
#pragma unroll
    for (int am = 0; am < 2; ++am)
#pragma unroll
      for (int bn = 0; bn < 2; ++bn)
        acc[am][bn] = __builtin_amdgcn_mfma_f32_16x16x32_bf16(
            af[am], bfv[bn], acc[am][bn], 0, 0, 0);
    __syncthreads();
    buf ^= 1;
  }

  if (MODE == 0) {
#pragma unroll
    for (int am = 0; am < 2; ++am)
#pragma unroll
      for (int i = 0; i < 4; ++i) {
        int grow = m0 + wr * 32 + am * 16 + g * 4 + i;
#pragma unroll
        for (int bn = 0; bn < 2; ++bn) {
          int gcol = n0 + wc * 32 + bn * 16 + li;
          Cb[(size_t)grow * DD + gcol] = f2bf(acc[am][bn][i]);
        }
      }
  } else {
    const float sbb = ws[WS_SC + 2];
    float ev[2];
#pragma unroll
    for (int bn = 0; bn < 2; ++bn)
      ev[bn] = ws[WS_E + b * NS + n0 + wc * 32 + bn * 16 + li];
#pragma unroll
    for (int am = 0; am < 2; ++am)
#pragma unroll
      for (int i = 0; i < 4; ++i) {
        int p = m0 + wr * 32 + am * 16 + g * 4 + i;
        float av = ws[WS_A + b * NP + p] + sbb;
#pragma unroll
        for (int bn = 0; bn < 2; ++bn) {
          int s = n0 + wc * 32 + bn * 16 + li;
          size_t idx = ((size_t)b * NP + p) * NS + s;
          float sc = fmaf(acc[am][bn][i] + av + ev[bn], INV64, sbias[idx]);
          out[OUT_SCORES + idx] = (maskp[idx] == 0) ? NEGBIG : sc;
        }
      }
  }
}

// ---------------- kF: row softmax -> tv (4 rows per 256-thr block) -----------
__global__ __launch_bounds__(256) void kF(const float* __restrict__ scores,
                                          const float* __restrict__ vv,
                                          float* __restrict__ tv) {
  int row = blockIdx.x * 4 + (threadIdx.x >> 6);  // b*512+p
  int bb = row >> 9;
  int lane = threadIdx.x & 63;
  const float* sr = scores + (size_t)row * NS;
  const float* vr = vv + bb * NS;
  float4 s0 = *(const float4*)&sr[lane * 4];
  float4 s1 = *(const float4*)&sr[256 + lane * 4];
  float m = fmaxf(fmaxf(fmaxf(s0.x, s0.y), fmaxf(s0.z, s0.w)),
                  fmaxf(fmaxf(s1.x, s1.y), fmaxf(s1.z, s1.w)));
#pragma unroll
  for (int o = 32; o; o >>= 1) m = fmaxf(m, __shfl_xor(m, o));
  float4 v0 = *(const float4*)&vr[lane * 4];
  float4 v1 = *(const float4*)&vr[256 + lane * 4];
  float z = 0.f, w = 0.f, e;
  e = exp2f((s0.x - m) * LOG2E); z += e; w += e * v0.x;
  e = exp2f((s0.y - m) * LOG2E); z += e; w += e * v0.y;
  e = exp2f((s0.z - m) * LOG2E); z += e; w += e * v0.z;
  e = exp2f((s0.w - m) * LOG2E); z += e; w += e * v0.w;
  e = exp2f((s1.x - m) * LOG2E); z += e; w += e * v1.x;
  e = exp2f((s1.y - m) * LOG2E); z += e; w += e * v1.y;
  e = exp2f((s1.z - m) * LOG2E); z += e; w += e * v1.z;
  e = exp2f((s1.w - m) * LOG2E); z += e; w += e * v1.w;
#pragma unroll
  for (int o = 32; o; o >>= 1) {
    z += __shfl_xor(z, o);
    w += __shfl_xor(w, o);
  }
  if (lane == 0) tv[row] = (w / z) * (1.0f / NP);
}

// ---------------- kG: compatibility write + value reduce ---------------------
__global__ __launch_bounds__(256) void kG(const float* __restrict__ ws,
                                          const float* __restrict__ bc,
                                          float* __restrict__ out) {
  if (blockIdx.x < 2048) {
    int idx = blockIdx.x * 256 + threadIdx.x;
    int lin = idx << 2;
    int s = lin & (NS - 1);
    int p = (lin >> 9) & (NP - 1);
    int bb = lin >> 18;
    float cp = ws[WS_CP + bb * NP + p];
    float4 cs = *(const float4*)&ws[WS_CS + bb * NS + s];
    float bcv = *bc;
    float4 o = make_float4(cp + cs.x + bcv, cp + cs.y + bcv, cp + cs.z + bcv,
                           cp + cs.w + bcv);
    *(float4*)&out[OUT_COMP + lin] = o;
  } else {
    int wave = threadIdx.x >> 6, lane = threadIdx.x & 63;
    int bb = wave * 2 + (lane >> 5);
    int l32 = lane & 31;
    const float* tv = ws + WS_TV + bb * NP;
    float s = 0.f;
#pragma unroll
    for (int k = 0; k < 16; ++k) s += tv[k * 32 + l32];
#pragma unroll
    for (int o = 16; o; o >>= 1) s += __shfl_xor(s, o);
    if (l32 == 0) out[OUT_VALUE + bb] = s + ws[WS_SC + 1];
  }
}

extern "C" void kernel_launch(void* const* d_in, const int* in_sizes, int n_in,
                              void* d_out, int out_size, void* d_ws,
                              size_t ws_size, hipStream_t stream) {
  const float* piece = (const float*)d_in[0];
  const float* slot = (const float*)d_in[1];
  const int* mask = (const int*)d_in[2];
  const float* sbias = (const float*)d_in[3];
  const float* Wq = (const float*)d_in[4];
  const float* bq = (const float*)d_in[5];
  const float* Wk = (const float*)d_in[6];
  const float* bk = (const float*)d_in[7];
  const float* Wv = (const float*)d_in[8];
  const float* bv = (const float*)d_in[9];
  const float* Wo = (const float*)d_in[10];
  const float* bo = (const float*)d_in[11];
  const float* Wc = (const float*)d_in[12];
  const float* bc = (const float*)d_in[13];
  const float* Wval = (const float*)d_in[14];
  const float* bval = (const float*)d_in[15];
  float* out = (float*)d_out;
  float* ws = (float*)d_ws;

  short* pbf = (short*)out;               // piece bf16 in scores region (consumed by kD)
  short* tbf = (short*)(out + OUT_COMP);  // T bf16 in comp region (consumed by kE)
  short* sbf = (short*)(ws + WS_SLOTBF);
  short* wqb = (short*)(ws + WS_WQBF);
  short* wkb = (short*)(ws + WS_WKBF);
  short* mtb = (short*)(ws + WS_MTBF);

  hipLaunchKernelGGL(kA, dim3(641), dim3(256), 0, stream,
                     Wo, Wval, Wq, bk, Wk, bq, bo, bval, ws, wqb, wkb);
  hipLaunchKernelGGL(kB, dim3(161), dim3(256), 0, stream, Wv, bv, wkb, wqb, ws, mtb);
  hipLaunchKernelGGL(kC, dim3(2048), dim3(256), 0, stream, piece, slot, Wc, ws, pbf, sbf);
  // T = piece_bf . MT^T
  hipLaunchKernelGGL((k_gemm8<0>), dim3(32, 8), dim3(512), 0, stream,
                     pbf, mtb, tbf, (const float*)nullptr, (const float*)nullptr,
                     (const int*)nullptr, (float*)nullptr);
  // scores = T_bf . slot_bf^T + epilogue
  hipLaunchKernelGGL((k_gemm8<1>), dim3(4, 8, 8), dim3(512), 0, stream,
                     tbf, sbf, (short*)nullptr, ws, sbias, mask, out);
  hipLaunchKernelGGL(kF, dim3(1024), dim3(256), 0, stream, out, ws + WS_VV, ws + WS_TV);
  hipLaunchKernelGGL(kG, dim3(2049), dim3(256), 0, stream, ws, bc, out);
}